// Round 12
// baseline (137.618 us; speedup 1.0000x reference)
//
#include <hip/hip_runtime.h>
#include <hip/hip_bf16.h>
#include <math.h>

#define OUT0   2097152      // 4*1024*512 (output 0 size)
#define SP_EPS 1e-7f
#define INV_T  0.125f       // 1/sqrt(64)
#define LOG2E  1.4426950408889634f

typedef __attribute__((ext_vector_type(8))) short bf16x8;
typedef __attribute__((ext_vector_type(4))) float f32x4;

// ---------------- bf16 split helpers (RN-to-nearest-even) ------------------
__device__ __forceinline__ unsigned short f2bf(float f) {
  unsigned int b = __float_as_uint(f);
  return (unsigned short)((b + 0x7fffu + ((b >> 16) & 1u)) >> 16);
}
__device__ __forceinline__ float bf2f(unsigned short u) {
  return __uint_as_float(((unsigned int)u) << 16);
}

__device__ __forceinline__ float wred_sum(float v) {
#pragma unroll
  for (int o = 32; o > 0; o >>= 1) v += __shfl_xor(v, o);
  return v;
}

// ---------------- kernel 0: split-convert up to 3 weight matrices ----------
__global__ __launch_bounds__(256) void convW_kernel(
    const float* __restrict__ w0, const float* __restrict__ w1,
    const float* __restrict__ w2, unsigned short* __restrict__ dst)
{
  const int z = blockIdx.z;
  const float* src = (z == 0) ? w0 : (z == 1) ? w1 : w2;
  unsigned short* hi = dst + (size_t)z * (1u << 19);
  unsigned short* lo = hi + (1u << 18);
  const int i = (blockIdx.x * 256 + threadIdx.x) * 4;
  const float4 x = *(const float4*)(src + i);
  ushort4 h, l;
  h.x = f2bf(x.x); l.x = f2bf(x.x - bf2f(h.x));
  h.y = f2bf(x.y); l.y = f2bf(x.y - bf2f(h.y));
  h.z = f2bf(x.z); l.z = f2bf(x.z - bf2f(h.z));
  h.w = f2bf(x.w); l.w = f2bf(x.w - bf2f(h.w));
  *(ushort4*)(hi + i) = h;
  *(ushort4*)(lo + i) = l;
}

// ---------------- kernel 1: QKV projection via split-bf16 MFMA -------------
// BM=64, BN=128, BK=64; 4 waves (2x2). A (q/k/v f32) split in-register during
// staging; W pre-split. q,k out as hi/lo bf16; v out f32.
__global__ __launch_bounds__(256) void qkv_mfma_kernel(
    const float* __restrict__ q, const float* __restrict__ k, const float* __restrict__ v,
    const unsigned short* __restrict__ Wsplit,
    const float* __restrict__ bq, const float* __restrict__ bk, const float* __restrict__ bv,
    unsigned short* __restrict__ qhh, unsigned short* __restrict__ qhl,
    unsigned short* __restrict__ khh, unsigned short* __restrict__ khl,
    float* __restrict__ vh)
{
  __shared__ short Ash[64 * 64], Asl[64 * 64];
  __shared__ short Bsh[128 * 64], Bsl[128 * 64];
  const int z = blockIdx.z;
  const float* A = (z == 0) ? q : (z == 1) ? k : v;
  const unsigned short* Wh = Wsplit + (size_t)z * (1u << 19);
  const unsigned short* Wl = Wh + (1u << 18);
  const float* bias = (z == 0) ? bq : (z == 1) ? bk : bv;
  const int r0 = blockIdx.x * 64, n0 = blockIdx.y * 128;
  const int tid = threadIdx.x, lane = tid & 63, w = tid >> 6;
  const int wr = w >> 1, wc = w & 1;
  const int l15 = lane & 15, l4 = lane >> 4;

  f32x4 acc[2][4];
#pragma unroll
  for (int a = 0; a < 2; ++a)
#pragma unroll
    for (int b = 0; b < 4; ++b) acc[a][b] = (f32x4){0.f, 0.f, 0.f, 0.f};

  for (int kt = 0; kt < 8; ++kt) {
    __syncthreads();
#pragma unroll
    for (int p = 0; p < 2; ++p) {
      const int c = tid + p * 256, row = c >> 3, k8 = (c & 7) * 8;
      const float4 x0 = *(const float4*)(A + (size_t)(r0 + row) * 512 + kt * 64 + k8);
      const float4 x1 = *(const float4*)(A + (size_t)(r0 + row) * 512 + kt * 64 + k8 + 4);
      bf16x8 hv, lv;
      const float xs[8] = {x0.x, x0.y, x0.z, x0.w, x1.x, x1.y, x1.z, x1.w};
#pragma unroll
      for (int j = 0; j < 8; ++j) {
        const unsigned short h = f2bf(xs[j]);
        hv[j] = (short)h; lv[j] = (short)f2bf(xs[j] - bf2f(h));
      }
      const int si = row * 64 + (k8 ^ ((row & 7) << 3));
      *(bf16x8*)&Ash[si] = hv; *(bf16x8*)&Asl[si] = lv;
    }
#pragma unroll
    for (int p = 0; p < 4; ++p) {
      const int c = tid + p * 256, row = c >> 3, k8 = (c & 7) * 8;
      const size_t go = (size_t)(n0 + row) * 512 + kt * 64 + k8;
      const int si = row * 64 + (k8 ^ ((row & 7) << 3));
      *(bf16x8*)&Bsh[si] = *(const bf16x8*)(Wh + go);
      *(bf16x8*)&Bsl[si] = *(const bf16x8*)(Wl + go);
    }
    __syncthreads();
#pragma unroll
    for (int kf = 0; kf < 2; ++kf) {
      const int kb = kf * 32 + l4 * 8;
      bf16x8 ah[2], al2[2];
#pragma unroll
      for (int rb = 0; rb < 2; ++rb) {
        const int ar = wr * 32 + rb * 16 + l15;
        const int si = ar * 64 + (kb ^ ((ar & 7) << 3));
        ah[rb] = *(bf16x8*)&Ash[si]; al2[rb] = *(bf16x8*)&Asl[si];
      }
#pragma unroll
      for (int cb = 0; cb < 4; ++cb) {
        const int br = wc * 64 + cb * 16 + l15;
        const int si = br * 64 + (kb ^ ((br & 7) << 3));
        const bf16x8 bh = *(bf16x8*)&Bsh[si];
        const bf16x8 bl = *(bf16x8*)&Bsl[si];
#pragma unroll
        for (int rb = 0; rb < 2; ++rb) {
          acc[rb][cb] = __builtin_amdgcn_mfma_f32_16x16x32_bf16(al2[rb], bh, acc[rb][cb], 0, 0, 0);
          acc[rb][cb] = __builtin_amdgcn_mfma_f32_16x16x32_bf16(ah[rb], bl, acc[rb][cb], 0, 0, 0);
          acc[rb][cb] = __builtin_amdgcn_mfma_f32_16x16x32_bf16(ah[rb], bh, acc[rb][cb], 0, 0, 0);
        }
      }
    }
  }
  unsigned short* H = (z == 0) ? qhh : khh;
  unsigned short* L = (z == 0) ? qhl : khl;
#pragma unroll
  for (int cb = 0; cb < 4; ++cb) {
    const int col = n0 + wc * 64 + cb * 16 + l15;
    const float bia = bias[col];
    const int h = col >> 6, d = col & 63;
#pragma unroll
    for (int rb = 0; rb < 2; ++rb)
#pragma unroll
      for (int ri = 0; ri < 4; ++ri) {
        const int row = r0 + wr * 32 + rb * 16 + l4 * 4 + ri;
        const int b = row >> 10, ll = row & 1023;
        const size_t idx = ((size_t)(h * 4 + b) << 16) + (ll << 6) + d;
        const float val = acc[rb][cb][ri] + bia;
        if (z == 2) {
          vh[idx] = val;
        } else {
          const unsigned short hv = f2bf(val);
          H[idx] = hv;
          L[idx] = f2bf(val - bf2f(hv));
        }
      }
  }
}

// ---------------- kernel 2: scores via split-bf16 MFMA ---------------------
// per bh: Q(1024x64) @ K(1024x64)^T / 8; BM=BN=64, K=64, 4 waves 2x2.
// Epilogue: stage the 64x64 f32 tile in (dead) Q/K LDS, then write out as
// float4s so every 16-lane group stores a 256B contiguous run.
__global__ __launch_bounds__(256) void scores_mfma_kernel(
    const unsigned short* __restrict__ qhh, const unsigned short* __restrict__ qhl,
    const unsigned short* __restrict__ khh, const unsigned short* __restrict__ khl,
    float* __restrict__ attn)
{
  __shared__ short smem[4][64 * 64];   // Qh/Ql/Kh/Kl; reused as 64x64 f32 C tile
  short* Qh = smem[0];
  short* Ql = smem[1];
  short* Kh = smem[2];
  short* Kl = smem[3];
  const int bh = blockIdx.z;
  const int r0 = blockIdx.x * 64, c0 = blockIdx.y * 64;
  const int tid = threadIdx.x, lane = tid & 63, w = tid >> 6;
  const int wr = w >> 1, wc = w & 1;
  const int l15 = lane & 15, l4 = lane >> 4;
  const size_t base = (size_t)bh << 16;
#pragma unroll
  for (int p = 0; p < 2; ++p) {
    const int c = tid + p * 256, row = c >> 3, k8 = (c & 7) * 8;
    const int si = row * 64 + (k8 ^ ((row & 7) << 3));
    *(bf16x8*)&Qh[si] = *(const bf16x8*)(qhh + base + (size_t)(r0 + row) * 64 + k8);
    *(bf16x8*)&Ql[si] = *(const bf16x8*)(qhl + base + (size_t)(r0 + row) * 64 + k8);
    *(bf16x8*)&Kh[si] = *(const bf16x8*)(khh + base + (size_t)(c0 + row) * 64 + k8);
    *(bf16x8*)&Kl[si] = *(const bf16x8*)(khl + base + (size_t)(c0 + row) * 64 + k8);
  }
  __syncthreads();
  f32x4 acc[2][2];
#pragma unroll
  for (int a = 0; a < 2; ++a)
#pragma unroll
    for (int b = 0; b < 2; ++b) acc[a][b] = (f32x4){0.f, 0.f, 0.f, 0.f};
#pragma unroll
  for (int kf = 0; kf < 2; ++kf) {
    const int kb = kf * 32 + l4 * 8;
    bf16x8 ah[2], al2[2];
#pragma unroll
    for (int rb = 0; rb < 2; ++rb) {
      const int ar = wr * 32 + rb * 16 + l15;
      const int si = ar * 64 + (kb ^ ((ar & 7) << 3));
      ah[rb] = *(bf16x8*)&Qh[si]; al2[rb] = *(bf16x8*)&Ql[si];
    }
#pragma unroll
    for (int cb = 0; cb < 2; ++cb) {
      const int br = wc * 32 + cb * 16 + l15;
      const int si = br * 64 + (kb ^ ((br & 7) << 3));
      const bf16x8 bh8 = *(bf16x8*)&Kh[si];
      const bf16x8 bl8 = *(bf16x8*)&Kl[si];
#pragma unroll
      for (int rb = 0; rb < 2; ++rb) {
        acc[rb][cb] = __builtin_amdgcn_mfma_f32_16x16x32_bf16(al2[rb], bh8, acc[rb][cb], 0, 0, 0);
        acc[rb][cb] = __builtin_amdgcn_mfma_f32_16x16x32_bf16(ah[rb], bl8, acc[rb][cb], 0, 0, 0);
        acc[rb][cb] = __builtin_amdgcn_mfma_f32_16x16x32_bf16(ah[rb], bh8, acc[rb][cb], 0, 0, 0);
      }
    }
  }
  // ---- stage C tile in LDS (Q/K tiles are dead), then coalesced write ----
  __syncthreads();
  float* Cs = (float*)smem;            // 64x64 f32 = 16 KB (of 32 KB)
#pragma unroll
  for (int cb = 0; cb < 2; ++cb) {
    const int col = wc * 32 + cb * 16 + l15;
#pragma unroll
    for (int rb = 0; rb < 2; ++rb)
#pragma unroll
      for (int ri = 0; ri < 4; ++ri) {
        const int row = wr * 32 + rb * 16 + l4 * 4 + ri;
        Cs[row * 64 + col] = acc[rb][cb][ri] * INV_T;
      }
  }
  __syncthreads();
  float* outp = attn + ((size_t)bh << 20) + (size_t)r0 * 1024 + c0;
#pragma unroll
  for (int p = 0; p < 4; ++p) {
    const int i = tid + p * 256;       // 0..1023 float4 slots
    const int row = i >> 4, c4 = (i & 15) * 4;
    *(float4*)(outp + (size_t)row * 1024 + c4) = *(const float4*)&Cs[row * 64 + c4];
  }
}

// ---------------- kernel 3: softmax + top-6 sparsify + sparse PV -----------
// Wave-synchronous, branch-free, NO max-subtraction (u = exp2(s8*log2e) is
// overflow-safe: |s/8| <~ 14). w = (u-u6-eps*Z)+ / (S+eps*Z) is exactly the
// reference formula divided through by Z.
__global__ __launch_bounds__(256) void sparse_row_kernel(
    float* __restrict__ attn, const float* __restrict__ vh,
    unsigned short* __restrict__ ofhi, unsigned short* __restrict__ oflo)
{
  const int tid  = threadIdx.x;
  const int wv   = tid >> 6, lane = tid & 63;
  const int row  = blockIdx.x * 4 + wv;          // bh*1024 + lq
  const int bh   = row >> 10, lq = row & 1023;
  float* rp = attn + ((size_t)row << 10);
  __shared__ float s_w[4][8];
  __shared__ int   s_i[4][8];

  float u[16];
  {
    const float4 t0 = *(const float4*)(rp + lane * 4);
    const float4 t1 = *(const float4*)(rp + 256 + lane * 4);
    const float4 t2 = *(const float4*)(rp + 512 + lane * 4);
    const float4 t3 = *(const float4*)(rp + 768 + lane * 4);
    u[0]=t0.x; u[1]=t0.y; u[2]=t0.z; u[3]=t0.w;
    u[4]=t1.x; u[5]=t1.y; u[6]=t1.z; u[7]=t1.w;
    u[8]=t2.x; u[9]=t2.y; u[10]=t2.z; u[11]=t2.w;
    u[12]=t3.x; u[13]=t3.y; u[14]=t3.z; u[15]=t3.w;
  }

  float Zl = 0.f;
#pragma unroll
  for (int j = 0; j < 16; ++j) { u[j] = exp2f(u[j] * LOG2E); Zl += u[j]; }
  const float Z = wred_sum(Zl);

  // lane-local top-6 sorted desc (insertion network, uniform)
  float t0 = -1e30f, t1 = -1e30f, t2 = -1e30f, t3 = -1e30f, t4 = -1e30f, t5 = -1e30f;
#pragma unroll
  for (int j = 0; j < 16; ++j) {
    float v = u[j], a;
    a = fmaxf(t0, v); v = fminf(t0, v); t0 = a;
    a = fmaxf(t1, v); v = fminf(t1, v); t1 = a;
    a = fmaxf(t2, v); v = fminf(t2, v); t2 = a;
    a = fmaxf(t3, v); v = fminf(t3, v); t3 = a;
    a = fmaxf(t4, v); v = fminf(t4, v); t4 = a;
    t5 = fmaxf(t5, v);
  }
  // butterfly merge of sorted-6 lists across 64 lanes
#pragma unroll
  for (int off = 1; off < 64; off <<= 1) {
    const float b0 = __shfl_xor(t0, off), b1 = __shfl_xor(t1, off),
                b2 = __shfl_xor(t2, off), b3 = __shfl_xor(t3, off),
                b4 = __shfl_xor(t4, off), b5 = __shfl_xor(t5, off);
    float m0 = fmaxf(t0, b5), m1 = fmaxf(t1, b4), m2 = fmaxf(t2, b3),
          m3 = fmaxf(t3, b2), m4 = fmaxf(t4, b1), m5 = fmaxf(t5, b0);
    float a;
    a = fmaxf(m0, m3); m3 = fminf(m0, m3); m0 = a;
    a = fmaxf(m1, m4); m4 = fminf(m1, m4); m1 = a;
    a = fmaxf(m2, m5); m5 = fminf(m2, m5); m2 = a;
    a = fmaxf(m0, m1); m1 = fminf(m0, m1); m0 = a;
    a = fmaxf(m0, m2); m2 = fminf(m0, m2); m0 = a;
    a = fmaxf(m1, m2); m2 = fminf(m1, m2); m1 = a;
    a = fmaxf(m3, m4); m4 = fminf(m3, m4); m3 = a;
    a = fmaxf(m3, m5); m5 = fminf(m3, m5); m3 = a;
    a = fmaxf(m4, m5); m5 = fminf(m4, m5); m4 = a;
    t0 = m0; t1 = m1; t2 = m2; t3 = m3; t4 = m4; t5 = m5;
  }

  const float du = t5 + SP_EPS * Z;
  float w[16], Sl = 0.f;
#pragma unroll
  for (int j = 0; j < 16; ++j) { w[j] = fmaxf(u[j] - du, 0.f); Sl += w[j]; }
  const float S = wred_sum(Sl);
  const float inv = 1.0f / (S + SP_EPS * Z);
#pragma unroll
  for (int j = 0; j < 16; ++j) w[j] *= inv;

  *(float4*)(rp +       lane * 4) = make_float4(w[0],  w[1],  w[2],  w[3]);
  *(float4*)(rp + 256 + lane * 4) = make_float4(w[4],  w[5],  w[6],  w[7]);
  *(float4*)(rp + 512 + lane * 4) = make_float4(w[8],  w[9],  w[10], w[11]);
  *(float4*)(rp + 768 + lane * 4) = make_float4(w[12], w[13], w[14], w[15]);

  int base = 0;
#pragma unroll
  for (int j = 0; j < 16; ++j) {
    const unsigned long long b = __ballot(w[j] > 0.f);
    if (w[j] > 0.f) {
      const int pos = base + __popcll(b & ((1ull << lane) - 1ull));
      if (pos < 8) { s_w[wv][pos] = w[j]; s_i[wv][pos] = (j >> 2) * 256 + lane * 4 + (j & 3); }
    }
    base += __popcll(b);
  }
  if (base > 8) base = 8;

  float acc = 0.f;
  const float* vb = vh + ((size_t)bh << 16);
  for (int t = 0; t < base; ++t)
    acc = fmaf(s_w[wv][t], vb[((size_t)s_i[wv][t] << 6) + lane], acc);
  const int b_ = bh & 3, h = bh >> 2;
  const int idx = (((b_ << 10) | lq) << 9) + (h << 6) + lane;
  const unsigned short hv = f2bf(acc);
  ofhi[idx] = hv;
  oflo[idx] = f2bf(acc - bf2f(hv));
}

// ---------------- kernel 4: fc+gate via split-bf16 MFMA + fused epilogue ---
__global__ __launch_bounds__(256) void out_proj_mfma_kernel(
    const unsigned short* __restrict__ ofhi, const unsigned short* __restrict__ oflo,
    const unsigned short* __restrict__ FG,
    const float* __restrict__ bfc, const float* __restrict__ bg,
    float* __restrict__ out)
{
  __shared__ short Ash[64 * 64], Asl[64 * 64];
  __shared__ short Bfh[128 * 64], Bfl[128 * 64];
  __shared__ short Bgh[128 * 64], Bgl[128 * 64];
  const unsigned short* Wfh = FG;
  const unsigned short* Wfl = FG + (1u << 18);
  const unsigned short* Wgh = FG + (2u << 18);
  const unsigned short* Wgl = FG + 3u * (1u << 18);
  const int r0 = blockIdx.x * 64, n0 = blockIdx.y * 128;
  const int tid = threadIdx.x, lane = tid & 63, w = tid >> 6;
  const int wr = w >> 1, wc = w & 1;
  const int l15 = lane & 15, l4 = lane >> 4;

  f32x4 accf[2][4], accg[2][4];
#pragma unroll
  for (int a = 0; a < 2; ++a)
#pragma unroll
    for (int b = 0; b < 4; ++b) {
      accf[a][b] = (f32x4){0.f, 0.f, 0.f, 0.f};
      accg[a][b] = (f32x4){0.f, 0.f, 0.f, 0.f};
    }

  for (int kt = 0; kt < 8; ++kt) {
    __syncthreads();
#pragma unroll
    for (int p = 0; p < 2; ++p) {
      const int c = tid + p * 256, row = c >> 3, k8 = (c & 7) * 8;
      const size_t go = (size_t)(r0 + row) * 512 + kt * 64 + k8;
      const int si = row * 64 + (k8 ^ ((row & 7) << 3));
      *(bf16x8*)&Ash[si] = *(const bf16x8*)(ofhi + go);
      *(bf16x8*)&Asl[si] = *(const bf16x8*)(oflo + go);
    }
#pragma unroll
    for (int p = 0; p < 4; ++p) {
      const int c = tid + p * 256, row = c >> 3, k8 = (c & 7) * 8;
      const int si = row * 64 + (k8 ^ ((row & 7) << 3));
      const size_t go = (size_t)(n0 + row) * 512 + kt * 64 + k8;
      *(bf16x8*)&Bfh[si] = *(const bf16x8*)(Wfh + go);
      *(bf16x8*)&Bfl[si] = *(const bf16x8*)(Wfl + go);
      *(bf16x8*)&Bgh[si] = *(const bf16x8*)(Wgh + go);
      *(bf16x8*)&Bgl[si] = *(const bf16x8*)(Wgl + go);
    }
    __syncthreads();
#pragma unroll
    for (int kf = 0; kf < 2; ++kf) {
      const int kb = kf * 32 + l4 * 8;
      bf16x8 ah[2], al2[2];
#pragma unroll
      for (int rb = 0; rb < 2; ++rb) {
        const int ar = wr * 32 + rb * 16 + l15;
        const int si = ar * 64 + (kb ^ ((ar & 7) << 3));
        ah[rb] = *(bf16x8*)&Ash[si]; al2[rb] = *(bf16x8*)&Asl[si];
      }
#pragma unroll
      for (int cb = 0; cb < 4; ++cb) {
        const int br = wc * 64 + cb * 16 + l15;
        const int si = br * 64 + (kb ^ ((br & 7) << 3));
        const bf16x8 fh = *(bf16x8*)&Bfh[si];
        const bf16x8 fl = *(bf16x8*)&Bfl[si];
        const bf16x8 gh = *(bf16x8*)&Bgh[si];
        const bf16x8 gl = *(bf16x8*)&Bgl[si];
#pragma unroll
        for (int rb = 0; rb < 2; ++rb) {
          accf[rb][cb] = __builtin_amdgcn_mfma_f32_16x16x32_bf16(al2[rb], fh, accf[rb][cb], 0, 0, 0);
          accf[rb][cb] = __builtin_amdgcn_mfma_f32_16x16x32_bf16(ah[rb], fl, accf[rb][cb], 0, 0, 0);
          accf[rb][cb] = __builtin_amdgcn_mfma_f32_16x16x32_bf16(ah[rb], fh, accf[rb][cb], 0, 0, 0);
          accg[rb][cb] = __builtin_amdgcn_mfma_f32_16x16x32_bf16(al2[rb], gh, accg[rb][cb], 0, 0, 0);
          accg[rb][cb] = __builtin_amdgcn_mfma_f32_16x16x32_bf16(ah[rb], gl, accg[rb][cb], 0, 0, 0);
          accg[rb][cb] = __builtin_amdgcn_mfma_f32_16x16x32_bf16(ah[rb], gh, accg[rb][cb], 0, 0, 0);
        }
      }
    }
  }
#pragma unroll
  for (int cb = 0; cb < 4; ++cb) {
    const int col = n0 + wc * 64 + cb * 16 + l15;
    const float bf4 = bfc[col];
    const float bg4 = bg[col];
#pragma unroll
    for (int rb = 0; rb < 2; ++rb)
#pragma unroll
      for (int ri = 0; ri < 4; ++ri) {
        const int row = r0 + wr * 32 + rb * 16 + l4 * 4 + ri;
        const float f = accf[rb][cb][ri] + bf4;
        const float g = accg[rb][cb][ri] + bg4;
        out[(size_t)row * 512 + col] = tanhf(f) / (1.f + __expf(-g));
      }
  }
}

extern "C" void kernel_launch(void* const* d_in, const int* in_sizes, int n_in,
                              void* d_out, int out_size, void* d_ws, size_t ws_size,
                              hipStream_t stream) {
  const float* q   = (const float*)d_in[0];
  const float* k   = (const float*)d_in[1];
  const float* v   = (const float*)d_in[2];
  const float* Wq  = (const float*)d_in[3];
  const float* bq  = (const float*)d_in[4];
  const float* Wk  = (const float*)d_in[5];
  const float* bk  = (const float*)d_in[6];
  const float* Wv  = (const float*)d_in[7];
  const float* bv  = (const float*)d_in[8];
  const float* Wfc = (const float*)d_in[9];
  const float* bfc = (const float*)d_in[10];
  const float* Wg  = (const float*)d_in[11];
  const float* bg  = (const float*)d_in[12];

  float* out  = (float*)d_out;
  float* attn = out + OUT0;                 // (32,1024,1024) score scratch then final

  // qh splits live in the out0 region (8MB, overwritten by out_proj at the end)
  unsigned short* qhh = (unsigned short*)d_out;
  unsigned short* qhl = qhh + (1u << 21);

  // ws (24MB): [0,8M) khh/khl -> later FG; [8,16M) vh; [16M..) Wqkv -> ofhi/oflo
  char* wsb = (char*)d_ws;
  unsigned short* khh  = (unsigned short*)wsb;
  unsigned short* khl  = (unsigned short*)(wsb + (4u << 20));
  float*          vh   = (float*)(wsb + (8u << 20));
  unsigned short* Wqkv = (unsigned short*)(wsb + (16u << 20));
  unsigned short* ofhi = (unsigned short*)(wsb + (16u << 20));
  unsigned short* oflo = (unsigned short*)(wsb + (20u << 20));
  unsigned short* FG   = (unsigned short*)wsb;

  convW_kernel<<<dim3(256, 1, 3), 256, 0, stream>>>(Wq, Wk, Wv, Wqkv);
  qkv_mfma_kernel<<<dim3(64, 4, 3), 256, 0, stream>>>(q, k, v, Wqkv, bq, bk, bv,
                                                      qhh, qhl, khh, khl, vh);
  scores_mfma_kernel<<<dim3(16, 16, 32), 256, 0, stream>>>(qhh, qhl, khh, khl, attn);
  convW_kernel<<<dim3(256, 1, 2), 256, 0, stream>>>(Wfc, Wg, Wg, FG);
  sparse_row_kernel<<<dim3(8192), 256, 0, stream>>>(attn, vh, ofhi, oflo);
  out_proj_mfma_kernel<<<dim3(64, 4), 256, 0, stream>>>(ofhi, oflo, FG, bfc, bg, out);
}

// Round 13
// 134.591 us; speedup vs baseline: 1.0225x; 1.0225x over previous
//
#include <hip/hip_runtime.h>
#include <hip/hip_bf16.h>
#include <math.h>

#define OUT0   2097152      // 4*1024*512 (output 0 size)
#define SP_EPS 1e-7f
#define INV_T  0.125f       // 1/sqrt(64)
#define LOG2E  1.4426950408889634f

typedef __attribute__((ext_vector_type(8))) short bf16x8;
typedef __attribute__((ext_vector_type(4))) float f32x4;

// ---------------- bf16 split helpers (RN-to-nearest-even) ------------------
__device__ __forceinline__ unsigned short f2bf(float f) {
  unsigned int b = __float_as_uint(f);
  return (unsigned short)((b + 0x7fffu + ((b >> 16) & 1u)) >> 16);
}
__device__ __forceinline__ float bf2f(unsigned short u) {
  return __uint_as_float(((unsigned int)u) << 16);
}

__device__ __forceinline__ float wred_sum(float v) {
#pragma unroll
  for (int o = 32; o > 0; o >>= 1) v += __shfl_xor(v, o);
  return v;
}

// merge two sorted-desc 6-lists -> top-6 of union, sorted desc (exact)
__device__ __forceinline__ void merge6(float a[6], const float b[6]) {
  float m0 = fmaxf(a[0], b[5]), m1 = fmaxf(a[1], b[4]), m2 = fmaxf(a[2], b[3]),
        m3 = fmaxf(a[3], b[2]), m4 = fmaxf(a[4], b[1]), m5 = fmaxf(a[5], b[0]);
  float x;
  x = fmaxf(m0, m3); m3 = fminf(m0, m3); m0 = x;
  x = fmaxf(m1, m4); m4 = fminf(m1, m4); m1 = x;
  x = fmaxf(m2, m5); m5 = fminf(m2, m5); m2 = x;
  x = fmaxf(m0, m1); m1 = fminf(m0, m1); m0 = x;
  x = fmaxf(m0, m2); m2 = fminf(m0, m2); m0 = x;
  x = fmaxf(m1, m2); m2 = fminf(m1, m2); m1 = x;
  x = fmaxf(m3, m4); m4 = fminf(m3, m4); m3 = x;
  x = fmaxf(m3, m5); m5 = fminf(m3, m5); m3 = x;
  x = fmaxf(m4, m5); m5 = fminf(m4, m5); m4 = x;
  a[0] = m0; a[1] = m1; a[2] = m2; a[3] = m3; a[4] = m4; a[5] = m5;
}

// ---------------- kernel 0: split-convert up to 3 weight matrices ----------
__global__ __launch_bounds__(256) void convW_kernel(
    const float* __restrict__ w0, const float* __restrict__ w1,
    const float* __restrict__ w2, unsigned short* __restrict__ dst)
{
  const int z = blockIdx.z;
  const float* src = (z == 0) ? w0 : (z == 1) ? w1 : w2;
  unsigned short* hi = dst + (size_t)z * (1u << 19);
  unsigned short* lo = hi + (1u << 18);
  const int i = (blockIdx.x * 256 + threadIdx.x) * 4;
  const float4 x = *(const float4*)(src + i);
  ushort4 h, l;
  h.x = f2bf(x.x); l.x = f2bf(x.x - bf2f(h.x));
  h.y = f2bf(x.y); l.y = f2bf(x.y - bf2f(h.y));
  h.z = f2bf(x.z); l.z = f2bf(x.z - bf2f(h.z));
  h.w = f2bf(x.w); l.w = f2bf(x.w - bf2f(h.w));
  *(ushort4*)(hi + i) = h;
  *(ushort4*)(lo + i) = l;
}

// ---------------- kernel 1: QKV projection via split-bf16 MFMA -------------
// BM=64, BN=128, BK=64; 4 waves (2x2). A (q/k/v f32) split in-register during
// staging; W pre-split. q,k out as hi/lo bf16; v out f32.
__global__ __launch_bounds__(256) void qkv_mfma_kernel(
    const float* __restrict__ q, const float* __restrict__ k, const float* __restrict__ v,
    const unsigned short* __restrict__ Wsplit,
    const float* __restrict__ bq, const float* __restrict__ bk, const float* __restrict__ bv,
    unsigned short* __restrict__ qhh, unsigned short* __restrict__ qhl,
    unsigned short* __restrict__ khh, unsigned short* __restrict__ khl,
    float* __restrict__ vh)
{
  __shared__ short Ash[64 * 64], Asl[64 * 64];
  __shared__ short Bsh[128 * 64], Bsl[128 * 64];
  const int z = blockIdx.z;
  const float* A = (z == 0) ? q : (z == 1) ? k : v;
  const unsigned short* Wh = Wsplit + (size_t)z * (1u << 19);
  const unsigned short* Wl = Wh + (1u << 18);
  const float* bias = (z == 0) ? bq : (z == 1) ? bk : bv;
  const int r0 = blockIdx.x * 64, n0 = blockIdx.y * 128;
  const int tid = threadIdx.x, lane = tid & 63, w = tid >> 6;
  const int wr = w >> 1, wc = w & 1;
  const int l15 = lane & 15, l4 = lane >> 4;

  f32x4 acc[2][4];
#pragma unroll
  for (int a = 0; a < 2; ++a)
#pragma unroll
    for (int b = 0; b < 4; ++b) acc[a][b] = (f32x4){0.f, 0.f, 0.f, 0.f};

  for (int kt = 0; kt < 8; ++kt) {
    __syncthreads();
#pragma unroll
    for (int p = 0; p < 2; ++p) {
      const int c = tid + p * 256, row = c >> 3, k8 = (c & 7) * 8;
      const float4 x0 = *(const float4*)(A + (size_t)(r0 + row) * 512 + kt * 64 + k8);
      const float4 x1 = *(const float4*)(A + (size_t)(r0 + row) * 512 + kt * 64 + k8 + 4);
      bf16x8 hv, lv;
      const float xs[8] = {x0.x, x0.y, x0.z, x0.w, x1.x, x1.y, x1.z, x1.w};
#pragma unroll
      for (int j = 0; j < 8; ++j) {
        const unsigned short h = f2bf(xs[j]);
        hv[j] = (short)h; lv[j] = (short)f2bf(xs[j] - bf2f(h));
      }
      const int si = row * 64 + (k8 ^ ((row & 7) << 3));
      *(bf16x8*)&Ash[si] = hv; *(bf16x8*)&Asl[si] = lv;
    }
#pragma unroll
    for (int p = 0; p < 4; ++p) {
      const int c = tid + p * 256, row = c >> 3, k8 = (c & 7) * 8;
      const size_t go = (size_t)(n0 + row) * 512 + kt * 64 + k8;
      const int si = row * 64 + (k8 ^ ((row & 7) << 3));
      *(bf16x8*)&Bsh[si] = *(const bf16x8*)(Wh + go);
      *(bf16x8*)&Bsl[si] = *(const bf16x8*)(Wl + go);
    }
    __syncthreads();
#pragma unroll
    for (int kf = 0; kf < 2; ++kf) {
      const int kb = kf * 32 + l4 * 8;
      bf16x8 ah[2], al2[2];
#pragma unroll
      for (int rb = 0; rb < 2; ++rb) {
        const int ar = wr * 32 + rb * 16 + l15;
        const int si = ar * 64 + (kb ^ ((ar & 7) << 3));
        ah[rb] = *(bf16x8*)&Ash[si]; al2[rb] = *(bf16x8*)&Asl[si];
      }
#pragma unroll
      for (int cb = 0; cb < 4; ++cb) {
        const int br = wc * 64 + cb * 16 + l15;
        const int si = br * 64 + (kb ^ ((br & 7) << 3));
        const bf16x8 bh = *(bf16x8*)&Bsh[si];
        const bf16x8 bl = *(bf16x8*)&Bsl[si];
#pragma unroll
        for (int rb = 0; rb < 2; ++rb) {
          acc[rb][cb] = __builtin_amdgcn_mfma_f32_16x16x32_bf16(al2[rb], bh, acc[rb][cb], 0, 0, 0);
          acc[rb][cb] = __builtin_amdgcn_mfma_f32_16x16x32_bf16(ah[rb], bl, acc[rb][cb], 0, 0, 0);
          acc[rb][cb] = __builtin_amdgcn_mfma_f32_16x16x32_bf16(ah[rb], bh, acc[rb][cb], 0, 0, 0);
        }
      }
    }
  }
  unsigned short* H = (z == 0) ? qhh : khh;
  unsigned short* L = (z == 0) ? qhl : khl;
#pragma unroll
  for (int cb = 0; cb < 4; ++cb) {
    const int col = n0 + wc * 64 + cb * 16 + l15;
    const float bia = bias[col];
    const int h = col >> 6, d = col & 63;
#pragma unroll
    for (int rb = 0; rb < 2; ++rb)
#pragma unroll
      for (int ri = 0; ri < 4; ++ri) {
        const int row = r0 + wr * 32 + rb * 16 + l4 * 4 + ri;
        const int b = row >> 10, ll = row & 1023;
        const size_t idx = ((size_t)(h * 4 + b) << 16) + (ll << 6) + d;
        const float val = acc[rb][cb][ri] + bia;
        if (z == 2) {
          vh[idx] = val;
        } else {
          const unsigned short hv = f2bf(val);
          H[idx] = hv;
          L[idx] = f2bf(val - bf2f(hv));
        }
      }
  }
}

// ---------------- kernel 2: scores via split-bf16 MFMA ---------------------
// per bh: Q(1024x64) @ K(1024x64)^T / 8; BM=BN=64, K=64, 4 waves 2x2.
// (R11 epilogue: direct scalar stores — measured best; LDS-staged variant
//  was neutral-negative in R12.)
__global__ __launch_bounds__(256) void scores_mfma_kernel(
    const unsigned short* __restrict__ qhh, const unsigned short* __restrict__ qhl,
    const unsigned short* __restrict__ khh, const unsigned short* __restrict__ khl,
    float* __restrict__ attn)
{
  __shared__ short Qh[64 * 64], Ql[64 * 64], Kh[64 * 64], Kl[64 * 64];
  const int bh = blockIdx.z;
  const int r0 = blockIdx.x * 64, c0 = blockIdx.y * 64;
  const int tid = threadIdx.x, lane = tid & 63, w = tid >> 6;
  const int wr = w >> 1, wc = w & 1;
  const int l15 = lane & 15, l4 = lane >> 4;
  const size_t base = (size_t)bh << 16;
#pragma unroll
  for (int p = 0; p < 2; ++p) {
    const int c = tid + p * 256, row = c >> 3, k8 = (c & 7) * 8;
    const int si = row * 64 + (k8 ^ ((row & 7) << 3));
    *(bf16x8*)&Qh[si] = *(const bf16x8*)(qhh + base + (size_t)(r0 + row) * 64 + k8);
    *(bf16x8*)&Ql[si] = *(const bf16x8*)(qhl + base + (size_t)(r0 + row) * 64 + k8);
    *(bf16x8*)&Kh[si] = *(const bf16x8*)(khh + base + (size_t)(c0 + row) * 64 + k8);
    *(bf16x8*)&Kl[si] = *(const bf16x8*)(khl + base + (size_t)(c0 + row) * 64 + k8);
  }
  __syncthreads();
  f32x4 acc[2][2];
#pragma unroll
  for (int a = 0; a < 2; ++a)
#pragma unroll
    for (int b = 0; b < 2; ++b) acc[a][b] = (f32x4){0.f, 0.f, 0.f, 0.f};
#pragma unroll
  for (int kf = 0; kf < 2; ++kf) {
    const int kb = kf * 32 + l4 * 8;
    bf16x8 ah[2], al2[2];
#pragma unroll
    for (int rb = 0; rb < 2; ++rb) {
      const int ar = wr * 32 + rb * 16 + l15;
      const int si = ar * 64 + (kb ^ ((ar & 7) << 3));
      ah[rb] = *(bf16x8*)&Qh[si]; al2[rb] = *(bf16x8*)&Ql[si];
    }
#pragma unroll
    for (int cb = 0; cb < 2; ++cb) {
      const int br = wc * 32 + cb * 16 + l15;
      const int si = br * 64 + (kb ^ ((br & 7) << 3));
      const bf16x8 bh8 = *(bf16x8*)&Kh[si];
      const bf16x8 bl8 = *(bf16x8*)&Kl[si];
#pragma unroll
      for (int rb = 0; rb < 2; ++rb) {
        acc[rb][cb] = __builtin_amdgcn_mfma_f32_16x16x32_bf16(al2[rb], bh8, acc[rb][cb], 0, 0, 0);
        acc[rb][cb] = __builtin_amdgcn_mfma_f32_16x16x32_bf16(ah[rb], bl8, acc[rb][cb], 0, 0, 0);
        acc[rb][cb] = __builtin_amdgcn_mfma_f32_16x16x32_bf16(ah[rb], bh8, acc[rb][cb], 0, 0, 0);
      }
    }
  }
  float* outp = attn + ((size_t)bh << 20);
#pragma unroll
  for (int cb = 0; cb < 2; ++cb) {
    const int col = c0 + wc * 32 + cb * 16 + l15;
#pragma unroll
    for (int rb = 0; rb < 2; ++rb)
#pragma unroll
      for (int ri = 0; ri < 4; ++ri) {
        const int row = r0 + wr * 32 + rb * 16 + l4 * 4 + ri;
        outp[(size_t)row * 1024 + col] = acc[rb][cb][ri] * INV_T;
      }
  }
}

// ---------------- kernel 3: softmax + top-6 sparsify + sparse PV -----------
// Wave-synchronous, branch-free, no max-subtraction. Lane-local top-6 built
// as TWO independent 8-element insertion chains (ILP=2, halved dependency
// chain) + exact merge6 — identical selected values, bit-identical output.
__global__ __launch_bounds__(256) void sparse_row_kernel(
    float* __restrict__ attn, const float* __restrict__ vh,
    unsigned short* __restrict__ ofhi, unsigned short* __restrict__ oflo)
{
  const int tid  = threadIdx.x;
  const int wv   = tid >> 6, lane = tid & 63;
  const int row  = blockIdx.x * 4 + wv;          // bh*1024 + lq
  const int bh   = row >> 10, lq = row & 1023;
  float* rp = attn + ((size_t)row << 10);
  __shared__ float s_w[4][8];
  __shared__ int   s_i[4][8];

  float u[16];
  {
    const float4 t0 = *(const float4*)(rp + lane * 4);
    const float4 t1 = *(const float4*)(rp + 256 + lane * 4);
    const float4 t2 = *(const float4*)(rp + 512 + lane * 4);
    const float4 t3 = *(const float4*)(rp + 768 + lane * 4);
    u[0]=t0.x; u[1]=t0.y; u[2]=t0.z; u[3]=t0.w;
    u[4]=t1.x; u[5]=t1.y; u[6]=t1.z; u[7]=t1.w;
    u[8]=t2.x; u[9]=t2.y; u[10]=t2.z; u[11]=t2.w;
    u[12]=t3.x; u[13]=t3.y; u[14]=t3.z; u[15]=t3.w;
  }

  float Zl = 0.f;
#pragma unroll
  for (int j = 0; j < 16; ++j) { u[j] = exp2f(u[j] * LOG2E); Zl += u[j]; }
  const float Z = wred_sum(Zl);

  // lane-local top-6: two independent 8-elem chains, then exact merge
  float ta[6], tb[6];
#pragma unroll
  for (int j = 0; j < 6; ++j) { ta[j] = -1e30f; tb[j] = -1e30f; }
#pragma unroll
  for (int j = 0; j < 8; ++j) {
    float va = u[j], vb = u[j + 8], a;
    a = fmaxf(ta[0], va); va = fminf(ta[0], va); ta[0] = a;
    a = fmaxf(tb[0], vb); vb = fminf(tb[0], vb); tb[0] = a;
    a = fmaxf(ta[1], va); va = fminf(ta[1], va); ta[1] = a;
    a = fmaxf(tb[1], vb); vb = fminf(tb[1], vb); tb[1] = a;
    a = fmaxf(ta[2], va); va = fminf(ta[2], va); ta[2] = a;
    a = fmaxf(tb[2], vb); vb = fminf(tb[2], vb); tb[2] = a;
    a = fmaxf(ta[3], va); va = fminf(ta[3], va); ta[3] = a;
    a = fmaxf(tb[3], vb); vb = fminf(tb[3], vb); tb[3] = a;
    a = fmaxf(ta[4], va); va = fminf(ta[4], va); ta[4] = a;
    a = fmaxf(tb[4], vb); vb = fminf(tb[4], vb); tb[4] = a;
    ta[5] = fmaxf(ta[5], va);
    tb[5] = fmaxf(tb[5], vb);
  }
  merge6(ta, tb);
  float t0 = ta[0], t1 = ta[1], t2 = ta[2], t3 = ta[3], t4 = ta[4], t5 = ta[5];

  // butterfly merge of sorted-6 lists across 64 lanes
#pragma unroll
  for (int off = 1; off < 64; off <<= 1) {
    const float b0 = __shfl_xor(t0, off), b1 = __shfl_xor(t1, off),
                b2 = __shfl_xor(t2, off), b3 = __shfl_xor(t3, off),
                b4 = __shfl_xor(t4, off), b5 = __shfl_xor(t5, off);
    float m0 = fmaxf(t0, b5), m1 = fmaxf(t1, b4), m2 = fmaxf(t2, b3),
          m3 = fmaxf(t3, b2), m4 = fmaxf(t4, b1), m5 = fmaxf(t5, b0);
    float a;
    a = fmaxf(m0, m3); m3 = fminf(m0, m3); m0 = a;
    a = fmaxf(m1, m4); m4 = fminf(m1, m4); m1 = a;
    a = fmaxf(m2, m5); m5 = fminf(m2, m5); m2 = a;
    a = fmaxf(m0, m1); m1 = fminf(m0, m1); m0 = a;
    a = fmaxf(m0, m2); m2 = fminf(m0, m2); m0 = a;
    a = fmaxf(m1, m2); m2 = fminf(m1, m2); m1 = a;
    a = fmaxf(m3, m4); m4 = fminf(m3, m4); m3 = a;
    a = fmaxf(m3, m5); m5 = fminf(m3, m5); m3 = a;
    a = fmaxf(m4, m5); m5 = fminf(m4, m5); m4 = a;
    t0 = m0; t1 = m1; t2 = m2; t3 = m3; t4 = m4; t5 = m5;
  }

  const float du = t5 + SP_EPS * Z;
  float w[16], Sl = 0.f;
#pragma unroll
  for (int j = 0; j < 16; ++j) { w[j] = fmaxf(u[j] - du, 0.f); Sl += w[j]; }
  const float S = wred_sum(Sl);
  const float inv = 1.0f / (S + SP_EPS * Z);
#pragma unroll
  for (int j = 0; j < 16; ++j) w[j] *= inv;

  *(float4*)(rp +       lane * 4) = make_float4(w[0],  w[1],  w[2],  w[3]);
  *(float4*)(rp + 256 + lane * 4) = make_float4(w[4],  w[5],  w[6],  w[7]);
  *(float4*)(rp + 512 + lane * 4) = make_float4(w[8],  w[9],  w[10], w[11]);
  *(float4*)(rp + 768 + lane * 4) = make_float4(w[12], w[13], w[14], w[15]);

  int base = 0;
#pragma unroll
  for (int j = 0; j < 16; ++j) {
    const unsigned long long b = __ballot(w[j] > 0.f);
    if (w[j] > 0.f) {
      const int pos = base + __popcll(b & ((1ull << lane) - 1ull));
      if (pos < 8) { s_w[wv][pos] = w[j]; s_i[wv][pos] = (j >> 2) * 256 + lane * 4 + (j & 3); }
    }
    base += __popcll(b);
  }
  if (base > 8) base = 8;

  float acc = 0.f;
  const float* vb = vh + ((size_t)bh << 16);
  for (int t = 0; t < base; ++t)
    acc = fmaf(s_w[wv][t], vb[((size_t)s_i[wv][t] << 6) + lane], acc);
  const int b_ = bh & 3, h = bh >> 2;
  const int idx = (((b_ << 10) | lq) << 9) + (h << 6) + lane;
  const unsigned short hv = f2bf(acc);
  ofhi[idx] = hv;
  oflo[idx] = f2bf(acc - bf2f(hv));
}

// ---------------- kernel 4: fc+gate via split-bf16 MFMA + fused epilogue ---
__global__ __launch_bounds__(256) void out_proj_mfma_kernel(
    const unsigned short* __restrict__ ofhi, const unsigned short* __restrict__ oflo,
    const unsigned short* __restrict__ FG,
    const float* __restrict__ bfc, const float* __restrict__ bg,
    float* __restrict__ out)
{
  __shared__ short Ash[64 * 64], Asl[64 * 64];
  __shared__ short Bfh[128 * 64], Bfl[128 * 64];
  __shared__ short Bgh[128 * 64], Bgl[128 * 64];
  const unsigned short* Wfh = FG;
  const unsigned short* Wfl = FG + (1u << 18);
  const unsigned short* Wgh = FG + (2u << 18);
  const unsigned short* Wgl = FG + 3u * (1u << 18);
  const int r0 = blockIdx.x * 64, n0 = blockIdx.y * 128;
  const int tid = threadIdx.x, lane = tid & 63, w = tid >> 6;
  const int wr = w >> 1, wc = w & 1;
  const int l15 = lane & 15, l4 = lane >> 4;

  f32x4 accf[2][4], accg[2][4];
#pragma unroll
  for (int a = 0; a < 2; ++a)
#pragma unroll
    for (int b = 0; b < 4; ++b) {
      accf[a][b] = (f32x4){0.f, 0.f, 0.f, 0.f};
      accg[a][b] = (f32x4){0.f, 0.f, 0.f, 0.f};
    }

  for (int kt = 0; kt < 8; ++kt) {
    __syncthreads();
#pragma unroll
    for (int p = 0; p < 2; ++p) {
      const int c = tid + p * 256, row = c >> 3, k8 = (c & 7) * 8;
      const size_t go = (size_t)(r0 + row) * 512 + kt * 64 + k8;
      const int si = row * 64 + (k8 ^ ((row & 7) << 3));
      *(bf16x8*)&Ash[si] = *(const bf16x8*)(ofhi + go);
      *(bf16x8*)&Asl[si] = *(const bf16x8*)(oflo + go);
    }
#pragma unroll
    for (int p = 0; p < 4; ++p) {
      const int c = tid + p * 256, row = c >> 3, k8 = (c & 7) * 8;
      const int si = row * 64 + (k8 ^ ((row & 7) << 3));
      const size_t go = (size_t)(n0 + row) * 512 + kt * 64 + k8;
      *(bf16x8*)&Bfh[si] = *(const bf16x8*)(Wfh + go);
      *(bf16x8*)&Bfl[si] = *(const bf16x8*)(Wfl + go);
      *(bf16x8*)&Bgh[si] = *(const bf16x8*)(Wgh + go);
      *(bf16x8*)&Bgl[si] = *(const bf16x8*)(Wgl + go);
    }
    __syncthreads();
#pragma unroll
    for (int kf = 0; kf < 2; ++kf) {
      const int kb = kf * 32 + l4 * 8;
      bf16x8 ah[2], al2[2];
#pragma unroll
      for (int rb = 0; rb < 2; ++rb) {
        const int ar = wr * 32 + rb * 16 + l15;
        const int si = ar * 64 + (kb ^ ((ar & 7) << 3));
        ah[rb] = *(bf16x8*)&Ash[si]; al2[rb] = *(bf16x8*)&Asl[si];
      }
#pragma unroll
      for (int cb = 0; cb < 4; ++cb) {
        const int br = wc * 64 + cb * 16 + l15;
        const int si = br * 64 + (kb ^ ((br & 7) << 3));
        const bf16x8 fh = *(bf16x8*)&Bfh[si];
        const bf16x8 fl = *(bf16x8*)&Bfl[si];
        const bf16x8 gh = *(bf16x8*)&Bgh[si];
        const bf16x8 gl = *(bf16x8*)&Bgl[si];
#pragma unroll
        for (int rb = 0; rb < 2; ++rb) {
          accf[rb][cb] = __builtin_amdgcn_mfma_f32_16x16x32_bf16(al2[rb], fh, accf[rb][cb], 0, 0, 0);
          accf[rb][cb] = __builtin_amdgcn_mfma_f32_16x16x32_bf16(ah[rb], fl, accf[rb][cb], 0, 0, 0);
          accf[rb][cb] = __builtin_amdgcn_mfma_f32_16x16x32_bf16(ah[rb], fh, accf[rb][cb], 0, 0, 0);
          accg[rb][cb] = __builtin_amdgcn_mfma_f32_16x16x32_bf16(al2[rb], gh, accg[rb][cb], 0, 0, 0);
          accg[rb][cb] = __builtin_amdgcn_mfma_f32_16x16x32_bf16(ah[rb], gl, accg[rb][cb], 0, 0, 0);
          accg[rb][cb] = __builtin_amdgcn_mfma_f32_16x16x32_bf16(ah[rb], gh, accg[rb][cb], 0, 0, 0);
        }
      }
    }
  }
#pragma unroll
  for (int cb = 0; cb < 4; ++cb) {
    const int col = n0 + wc * 64 + cb * 16 + l15;
    const float bf4 = bfc[col];
    const float bg4 = bg[col];
#pragma unroll
    for (int rb = 0; rb < 2; ++rb)
#pragma unroll
      for (int ri = 0; ri < 4; ++ri) {
        const int row = r0 + wr * 32 + rb * 16 + l4 * 4 + ri;
        const float f = accf[rb][cb][ri] + bf4;
        const float g = accg[rb][cb][ri] + bg4;
        out[(size_t)row * 512 + col] = tanhf(f) / (1.f + __expf(-g));
      }
  }
}

extern "C" void kernel_launch(void* const* d_in, const int* in_sizes, int n_in,
                              void* d_out, int out_size, void* d_ws, size_t ws_size,
                              hipStream_t stream) {
  const float* q   = (const float*)d_in[0];
  const float* k   = (const float*)d_in[1];
  const float* v   = (const float*)d_in[2];
  const float* Wq  = (const float*)d_in[3];
  const float* bq  = (const float*)d_in[4];
  const float* Wk  = (const float*)d_in[5];
  const float* bk  = (const float*)d_in[6];
  const float* Wv  = (const float*)d_in[7];
  const float* bv  = (const float*)d_in[8];
  const float* Wfc = (const float*)d_in[9];
  const float* bfc = (const float*)d_in[10];
  const float* Wg  = (const float*)d_in[11];
  const float* bg  = (const float*)d_in[12];

  float* out  = (float*)d_out;
  float* attn = out + OUT0;                 // (32,1024,1024) score scratch then final

  // qh splits live in the out0 region (8MB, overwritten by out_proj at the end)
  unsigned short* qhh = (unsigned short*)d_out;
  unsigned short* qhl = qhh + (1u << 21);

  // ws (24MB): [0,8M) khh/khl -> later FG; [8,16M) vh; [16M..) Wqkv -> ofhi/oflo
  char* wsb = (char*)d_ws;
  unsigned short* khh  = (unsigned short*)wsb;
  unsigned short* khl  = (unsigned short*)(wsb + (4u << 20));
  float*          vh   = (float*)(wsb + (8u << 20));
  unsigned short* Wqkv = (unsigned short*)(wsb + (16u << 20));
  unsigned short* ofhi = (unsigned short*)(wsb + (16u << 20));
  unsigned short* oflo = (unsigned short*)(wsb + (20u << 20));
  unsigned short* FG   = (unsigned short*)wsb;

  convW_kernel<<<dim3(256, 1, 3), 256, 0, stream>>>(Wq, Wk, Wv, Wqkv);
  qkv_mfma_kernel<<<dim3(64, 4, 3), 256, 0, stream>>>(q, k, v, Wqkv, bq, bk, bv,
                                                      qhh, qhl, khh, khl, vh);
  scores_mfma_kernel<<<dim3(16, 16, 32), 256, 0, stream>>>(qhh, qhl, khh, khl, attn);
  convW_kernel<<<dim3(256, 1, 2), 256, 0, stream>>>(Wfc, Wg, Wg, FG);
  sparse_row_kernel<<<dim3(8192), 256, 0, stream>>>(attn, vh, ofhi, oflo);
  out_proj_mfma_kernel<<<dim3(64, 4), 256, 0, stream>>>(ofhi, oflo, FG, bfc, bg, out);
}

// Round 14
// 134.391 us; speedup vs baseline: 1.0240x; 1.0015x over previous
//
#include <hip/hip_runtime.h>
#include <hip/hip_bf16.h>
#include <math.h>

#define OUT0   2097152      // 4*1024*512 (output 0 size)
#define SP_EPS 1e-7f
#define INV_T  0.125f       // 1/sqrt(64)
#define LOG2E  1.4426950408889634f

typedef __attribute__((ext_vector_type(8))) short bf16x8;
typedef __attribute__((ext_vector_type(4))) float f32x4;

// ---------------- bf16 split helpers (RN-to-nearest-even) ------------------
__device__ __forceinline__ unsigned short f2bf(float f) {
  unsigned int b = __float_as_uint(f);
  return (unsigned short)((b + 0x7fffu + ((b >> 16) & 1u)) >> 16);
}
__device__ __forceinline__ float bf2f(unsigned short u) {
  return __uint_as_float(((unsigned int)u) << 16);
}

__device__ __forceinline__ float wred_sum(float v) {
#pragma unroll
  for (int o = 32; o > 0; o >>= 1) v += __shfl_xor(v, o);
  return v;
}

// merge two sorted-desc 6-lists -> top-6 of union, sorted desc (exact)
__device__ __forceinline__ void merge6(float a[6], const float b[6]) {
  float m0 = fmaxf(a[0], b[5]), m1 = fmaxf(a[1], b[4]), m2 = fmaxf(a[2], b[3]),
        m3 = fmaxf(a[3], b[2]), m4 = fmaxf(a[4], b[1]), m5 = fmaxf(a[5], b[0]);
  float x;
  x = fmaxf(m0, m3); m3 = fminf(m0, m3); m0 = x;
  x = fmaxf(m1, m4); m4 = fminf(m1, m4); m1 = x;
  x = fmaxf(m2, m5); m5 = fminf(m2, m5); m2 = x;
  x = fmaxf(m0, m1); m1 = fminf(m0, m1); m0 = x;
  x = fmaxf(m0, m2); m2 = fminf(m0, m2); m0 = x;
  x = fmaxf(m1, m2); m2 = fminf(m1, m2); m1 = x;
  x = fmaxf(m3, m4); m4 = fminf(m3, m4); m3 = x;
  x = fmaxf(m3, m5); m5 = fminf(m3, m5); m3 = x;
  x = fmaxf(m4, m5); m5 = fminf(m4, m5); m4 = x;
  a[0] = m0; a[1] = m1; a[2] = m2; a[3] = m3; a[4] = m4; a[5] = m5;
}

// descending comparator
#define CMPD(x, y) { const float _t = fmaxf(x, y); y = fminf(x, y); x = _t; }

// ---------------- kernel 0: split-convert up to 3 weight matrices ----------
__global__ __launch_bounds__(256) void convW_kernel(
    const float* __restrict__ w0, const float* __restrict__ w1,
    const float* __restrict__ w2, unsigned short* __restrict__ dst)
{
  const int z = blockIdx.z;
  const float* src = (z == 0) ? w0 : (z == 1) ? w1 : w2;
  unsigned short* hi = dst + (size_t)z * (1u << 19);
  unsigned short* lo = hi + (1u << 18);
  const int i = (blockIdx.x * 256 + threadIdx.x) * 4;
  const float4 x = *(const float4*)(src + i);
  ushort4 h, l;
  h.x = f2bf(x.x); l.x = f2bf(x.x - bf2f(h.x));
  h.y = f2bf(x.y); l.y = f2bf(x.y - bf2f(h.y));
  h.z = f2bf(x.z); l.z = f2bf(x.z - bf2f(h.z));
  h.w = f2bf(x.w); l.w = f2bf(x.w - bf2f(h.w));
  *(ushort4*)(hi + i) = h;
  *(ushort4*)(lo + i) = l;
}

// ---------------- kernel 1: QKV projection via split-bf16 MFMA -------------
__global__ __launch_bounds__(256) void qkv_mfma_kernel(
    const float* __restrict__ q, const float* __restrict__ k, const float* __restrict__ v,
    const unsigned short* __restrict__ Wsplit,
    const float* __restrict__ bq, const float* __restrict__ bk, const float* __restrict__ bv,
    unsigned short* __restrict__ qhh, unsigned short* __restrict__ qhl,
    unsigned short* __restrict__ khh, unsigned short* __restrict__ khl,
    float* __restrict__ vh)
{
  __shared__ short Ash[64 * 64], Asl[64 * 64];
  __shared__ short Bsh[128 * 64], Bsl[128 * 64];
  const int z = blockIdx.z;
  const float* A = (z == 0) ? q : (z == 1) ? k : v;
  const unsigned short* Wh = Wsplit + (size_t)z * (1u << 19);
  const unsigned short* Wl = Wh + (1u << 18);
  const float* bias = (z == 0) ? bq : (z == 1) ? bk : bv;
  const int r0 = blockIdx.x * 64, n0 = blockIdx.y * 128;
  const int tid = threadIdx.x, lane = tid & 63, w = tid >> 6;
  const int wr = w >> 1, wc = w & 1;
  const int l15 = lane & 15, l4 = lane >> 4;

  f32x4 acc[2][4];
#pragma unroll
  for (int a = 0; a < 2; ++a)
#pragma unroll
    for (int b = 0; b < 4; ++b) acc[a][b] = (f32x4){0.f, 0.f, 0.f, 0.f};

  for (int kt = 0; kt < 8; ++kt) {
    __syncthreads();
#pragma unroll
    for (int p = 0; p < 2; ++p) {
      const int c = tid + p * 256, row = c >> 3, k8 = (c & 7) * 8;
      const float4 x0 = *(const float4*)(A + (size_t)(r0 + row) * 512 + kt * 64 + k8);
      const float4 x1 = *(const float4*)(A + (size_t)(r0 + row) * 512 + kt * 64 + k8 + 4);
      bf16x8 hv, lv;
      const float xs[8] = {x0.x, x0.y, x0.z, x0.w, x1.x, x1.y, x1.z, x1.w};
#pragma unroll
      for (int j = 0; j < 8; ++j) {
        const unsigned short h = f2bf(xs[j]);
        hv[j] = (short)h; lv[j] = (short)f2bf(xs[j] - bf2f(h));
      }
      const int si = row * 64 + (k8 ^ ((row & 7) << 3));
      *(bf16x8*)&Ash[si] = hv; *(bf16x8*)&Asl[si] = lv;
    }
#pragma unroll
    for (int p = 0; p < 4; ++p) {
      const int c = tid + p * 256, row = c >> 3, k8 = (c & 7) * 8;
      const size_t go = (size_t)(n0 + row) * 512 + kt * 64 + k8;
      const int si = row * 64 + (k8 ^ ((row & 7) << 3));
      *(bf16x8*)&Bsh[si] = *(const bf16x8*)(Wh + go);
      *(bf16x8*)&Bsl[si] = *(const bf16x8*)(Wl + go);
    }
    __syncthreads();
#pragma unroll
    for (int kf = 0; kf < 2; ++kf) {
      const int kb = kf * 32 + l4 * 8;
      bf16x8 ah[2], al2[2];
#pragma unroll
      for (int rb = 0; rb < 2; ++rb) {
        const int ar = wr * 32 + rb * 16 + l15;
        const int si = ar * 64 + (kb ^ ((ar & 7) << 3));
        ah[rb] = *(bf16x8*)&Ash[si]; al2[rb] = *(bf16x8*)&Asl[si];
      }
#pragma unroll
      for (int cb = 0; cb < 4; ++cb) {
        const int br = wc * 64 + cb * 16 + l15;
        const int si = br * 64 + (kb ^ ((br & 7) << 3));
        const bf16x8 bh = *(bf16x8*)&Bsh[si];
        const bf16x8 bl = *(bf16x8*)&Bsl[si];
#pragma unroll
        for (int rb = 0; rb < 2; ++rb) {
          acc[rb][cb] = __builtin_amdgcn_mfma_f32_16x16x32_bf16(al2[rb], bh, acc[rb][cb], 0, 0, 0);
          acc[rb][cb] = __builtin_amdgcn_mfma_f32_16x16x32_bf16(ah[rb], bl, acc[rb][cb], 0, 0, 0);
          acc[rb][cb] = __builtin_amdgcn_mfma_f32_16x16x32_bf16(ah[rb], bh, acc[rb][cb], 0, 0, 0);
        }
      }
    }
  }
  unsigned short* H = (z == 0) ? qhh : khh;
  unsigned short* L = (z == 0) ? qhl : khl;
#pragma unroll
  for (int cb = 0; cb < 4; ++cb) {
    const int col = n0 + wc * 64 + cb * 16 + l15;
    const float bia = bias[col];
    const int h = col >> 6, d = col & 63;
#pragma unroll
    for (int rb = 0; rb < 2; ++rb)
#pragma unroll
      for (int ri = 0; ri < 4; ++ri) {
        const int row = r0 + wr * 32 + rb * 16 + l4 * 4 + ri;
        const int b = row >> 10, ll = row & 1023;
        const size_t idx = ((size_t)(h * 4 + b) << 16) + (ll << 6) + d;
        const float val = acc[rb][cb][ri] + bia;
        if (z == 2) {
          vh[idx] = val;
        } else {
          const unsigned short hv = f2bf(val);
          H[idx] = hv;
          L[idx] = f2bf(val - bf2f(hv));
        }
      }
  }
}

// ---------------- kernel 2: scores via split-bf16 MFMA ---------------------
__global__ __launch_bounds__(256) void scores_mfma_kernel(
    const unsigned short* __restrict__ qhh, const unsigned short* __restrict__ qhl,
    const unsigned short* __restrict__ khh, const unsigned short* __restrict__ khl,
    float* __restrict__ attn)
{
  __shared__ short Qh[64 * 64], Ql[64 * 64], Kh[64 * 64], Kl[64 * 64];
  const int bh = blockIdx.z;
  const int r0 = blockIdx.x * 64, c0 = blockIdx.y * 64;
  const int tid = threadIdx.x, lane = tid & 63, w = tid >> 6;
  const int wr = w >> 1, wc = w & 1;
  const int l15 = lane & 15, l4 = lane >> 4;
  const size_t base = (size_t)bh << 16;
#pragma unroll
  for (int p = 0; p < 2; ++p) {
    const int c = tid + p * 256, row = c >> 3, k8 = (c & 7) * 8;
    const int si = row * 64 + (k8 ^ ((row & 7) << 3));
    *(bf16x8*)&Qh[si] = *(const bf16x8*)(qhh + base + (size_t)(r0 + row) * 64 + k8);
    *(bf16x8*)&Ql[si] = *(const bf16x8*)(qhl + base + (size_t)(r0 + row) * 64 + k8);
    *(bf16x8*)&Kh[si] = *(const bf16x8*)(khh + base + (size_t)(c0 + row) * 64 + k8);
    *(bf16x8*)&Kl[si] = *(const bf16x8*)(khl + base + (size_t)(c0 + row) * 64 + k8);
  }
  __syncthreads();
  f32x4 acc[2][2];
#pragma unroll
  for (int a = 0; a < 2; ++a)
#pragma unroll
    for (int b = 0; b < 2; ++b) acc[a][b] = (f32x4){0.f, 0.f, 0.f, 0.f};
#pragma unroll
  for (int kf = 0; kf < 2; ++kf) {
    const int kb = kf * 32 + l4 * 8;
    bf16x8 ah[2], al2[2];
#pragma unroll
    for (int rb = 0; rb < 2; ++rb) {
      const int ar = wr * 32 + rb * 16 + l15;
      const int si = ar * 64 + (kb ^ ((ar & 7) << 3));
      ah[rb] = *(bf16x8*)&Qh[si]; al2[rb] = *(bf16x8*)&Ql[si];
    }
#pragma unroll
    for (int cb = 0; cb < 2; ++cb) {
      const int br = wc * 32 + cb * 16 + l15;
      const int si = br * 64 + (kb ^ ((br & 7) << 3));
      const bf16x8 bh8 = *(bf16x8*)&Kh[si];
      const bf16x8 bl8 = *(bf16x8*)&Kl[si];
#pragma unroll
      for (int rb = 0; rb < 2; ++rb) {
        acc[rb][cb] = __builtin_amdgcn_mfma_f32_16x16x32_bf16(al2[rb], bh8, acc[rb][cb], 0, 0, 0);
        acc[rb][cb] = __builtin_amdgcn_mfma_f32_16x16x32_bf16(ah[rb], bl8, acc[rb][cb], 0, 0, 0);
        acc[rb][cb] = __builtin_amdgcn_mfma_f32_16x16x32_bf16(ah[rb], bh8, acc[rb][cb], 0, 0, 0);
      }
    }
  }
  float* outp = attn + ((size_t)bh << 20);
#pragma unroll
  for (int cb = 0; cb < 2; ++cb) {
    const int col = c0 + wc * 32 + cb * 16 + l15;
#pragma unroll
    for (int rb = 0; rb < 2; ++rb)
#pragma unroll
      for (int ri = 0; ri < 4; ++ri) {
        const int row = r0 + wr * 32 + rb * 16 + l4 * 4 + ri;
        outp[(size_t)row * 1024 + col] = acc[rb][cb][ri] * INV_T;
      }
  }
}

// ---------------- kernel 3: softmax + top-6 sparsify + sparse PV -----------
// Wave-synchronous, branch-free, no max-subtraction. Lane-local top-6 via
// 2x Batcher sort8 (19 comparators each) + exact merge6 — ~half the VALU ops
// of the insertion approach, bit-identical result.
__global__ __launch_bounds__(256) void sparse_row_kernel(
    float* __restrict__ attn, const float* __restrict__ vh,
    unsigned short* __restrict__ ofhi, unsigned short* __restrict__ oflo)
{
  const int tid  = threadIdx.x;
  const int wv   = tid >> 6, lane = tid & 63;
  const int row  = blockIdx.x * 4 + wv;          // bh*1024 + lq
  const int bh   = row >> 10, lq = row & 1023;
  float* rp = attn + ((size_t)row << 10);
  __shared__ float s_w[4][8];
  __shared__ int   s_i[4][8];

  float u[16];
  {
    const float4 t0 = *(const float4*)(rp + lane * 4);
    const float4 t1 = *(const float4*)(rp + 256 + lane * 4);
    const float4 t2 = *(const float4*)(rp + 512 + lane * 4);
    const float4 t3 = *(const float4*)(rp + 768 + lane * 4);
    u[0]=t0.x; u[1]=t0.y; u[2]=t0.z; u[3]=t0.w;
    u[4]=t1.x; u[5]=t1.y; u[6]=t1.z; u[7]=t1.w;
    u[8]=t2.x; u[9]=t2.y; u[10]=t2.z; u[11]=t2.w;
    u[12]=t3.x; u[13]=t3.y; u[14]=t3.z; u[15]=t3.w;
  }

  float Zl = 0.f;
#pragma unroll
  for (int j = 0; j < 16; ++j) { u[j] = exp2f(u[j] * LOG2E); Zl += u[j]; }
  const float Z = wred_sum(Zl);

  // lane-local top-6: two Batcher sort8 networks (desc) + exact merge6
  float a0=u[0],a1=u[1],a2=u[2],a3=u[3],a4=u[4],a5=u[5],a6=u[6],a7=u[7];
  CMPD(a0,a1) CMPD(a2,a3) CMPD(a4,a5) CMPD(a6,a7)
  CMPD(a0,a2) CMPD(a1,a3) CMPD(a4,a6) CMPD(a5,a7)
  CMPD(a1,a2) CMPD(a5,a6)
  CMPD(a0,a4) CMPD(a1,a5) CMPD(a2,a6) CMPD(a3,a7)
  CMPD(a2,a4) CMPD(a3,a5)
  CMPD(a1,a2) CMPD(a3,a4) CMPD(a5,a6)
  float b0=u[8],b1=u[9],b2=u[10],b3=u[11],b4=u[12],b5=u[13],b6=u[14],b7=u[15];
  CMPD(b0,b1) CMPD(b2,b3) CMPD(b4,b5) CMPD(b6,b7)
  CMPD(b0,b2) CMPD(b1,b3) CMPD(b4,b6) CMPD(b5,b7)
  CMPD(b1,b2) CMPD(b5,b6)
  CMPD(b0,b4) CMPD(b1,b5) CMPD(b2,b6) CMPD(b3,b7)
  CMPD(b2,b4) CMPD(b3,b5)
  CMPD(b1,b2) CMPD(b3,b4) CMPD(b5,b6)
  float ta[6] = {a0, a1, a2, a3, a4, a5};
  float tb[6] = {b0, b1, b2, b3, b4, b5};
  merge6(ta, tb);
  float t0 = ta[0], t1 = ta[1], t2 = ta[2], t3 = ta[3], t4 = ta[4], t5 = ta[5];

  // butterfly merge of sorted-6 lists across 64 lanes
#pragma unroll
  for (int off = 1; off < 64; off <<= 1) {
    const float c0 = __shfl_xor(t0, off), c1 = __shfl_xor(t1, off),
                c2 = __shfl_xor(t2, off), c3 = __shfl_xor(t3, off),
                c4 = __shfl_xor(t4, off), c5 = __shfl_xor(t5, off);
    float m0 = fmaxf(t0, c5), m1 = fmaxf(t1, c4), m2 = fmaxf(t2, c3),
          m3 = fmaxf(t3, c2), m4 = fmaxf(t4, c1), m5 = fmaxf(t5, c0);
    float a;
    a = fmaxf(m0, m3); m3 = fminf(m0, m3); m0 = a;
    a = fmaxf(m1, m4); m4 = fminf(m1, m4); m1 = a;
    a = fmaxf(m2, m5); m5 = fminf(m2, m5); m2 = a;
    a = fmaxf(m0, m1); m1 = fminf(m0, m1); m0 = a;
    a = fmaxf(m0, m2); m2 = fminf(m0, m2); m0 = a;
    a = fmaxf(m1, m2); m2 = fminf(m1, m2); m1 = a;
    a = fmaxf(m3, m4); m4 = fminf(m3, m4); m3 = a;
    a = fmaxf(m3, m5); m5 = fminf(m3, m5); m3 = a;
    a = fmaxf(m4, m5); m5 = fminf(m4, m5); m4 = a;
    t0 = m0; t1 = m1; t2 = m2; t3 = m3; t4 = m4; t5 = m5;
  }

  const float du = t5 + SP_EPS * Z;
  float w[16], Sl = 0.f;
#pragma unroll
  for (int j = 0; j < 16; ++j) { w[j] = fmaxf(u[j] - du, 0.f); Sl += w[j]; }
  const float S = wred_sum(Sl);
  const float inv = 1.0f / (S + SP_EPS * Z);
#pragma unroll
  for (int j = 0; j < 16; ++j) w[j] *= inv;

  *(float4*)(rp +       lane * 4) = make_float4(w[0],  w[1],  w[2],  w[3]);
  *(float4*)(rp + 256 + lane * 4) = make_float4(w[4],  w[5],  w[6],  w[7]);
  *(float4*)(rp + 512 + lane * 4) = make_float4(w[8],  w[9],  w[10], w[11]);
  *(float4*)(rp + 768 + lane * 4) = make_float4(w[12], w[13], w[14], w[15]);

  int base = 0;
#pragma unroll
  for (int j = 0; j < 16; ++j) {
    const unsigned long long b = __ballot(w[j] > 0.f);
    if (w[j] > 0.f) {
      const int pos = base + __popcll(b & ((1ull << lane) - 1ull));
      if (pos < 8) { s_w[wv][pos] = w[j]; s_i[wv][pos] = (j >> 2) * 256 + lane * 4 + (j & 3); }
    }
    base += __popcll(b);
  }
  if (base > 8) base = 8;

  float acc = 0.f;
  const float* vb = vh + ((size_t)bh << 16);
  for (int t = 0; t < base; ++t)
    acc = fmaf(s_w[wv][t], vb[((size_t)s_i[wv][t] << 6) + lane], acc);
  const int b_ = bh & 3, h = bh >> 2;
  const int idx = (((b_ << 10) | lq) << 9) + (h << 6) + lane;
  const unsigned short hv = f2bf(acc);
  ofhi[idx] = hv;
  oflo[idx] = f2bf(acc - bf2f(hv));
}

// ---------------- kernel 4: fc+gate via split-bf16 MFMA + fused epilogue ---
__global__ __launch_bounds__(256) void out_proj_mfma_kernel(
    const unsigned short* __restrict__ ofhi, const unsigned short* __restrict__ oflo,
    const unsigned short* __restrict__ FG,
    const float* __restrict__ bfc, const float* __restrict__ bg,
    float* __restrict__ out)
{
  __shared__ short Ash[64 * 64], Asl[64 * 64];
  __shared__ short Bfh[128 * 64], Bfl[128 * 64];
  __shared__ short Bgh[128 * 64], Bgl[128 * 64];
  const unsigned short* Wfh = FG;
  const unsigned short* Wfl = FG + (1u << 18);
  const unsigned short* Wgh = FG + (2u << 18);
  const unsigned short* Wgl = FG + 3u * (1u << 18);
  const int r0 = blockIdx.x * 64, n0 = blockIdx.y * 128;
  const int tid = threadIdx.x, lane = tid & 63, w = tid >> 6;
  const int wr = w >> 1, wc = w & 1;
  const int l15 = lane & 15, l4 = lane >> 4;

  f32x4 accf[2][4], accg[2][4];
#pragma unroll
  for (int a = 0; a < 2; ++a)
#pragma unroll
    for (int b = 0; b < 4; ++b) {
      accf[a][b] = (f32x4){0.f, 0.f, 0.f, 0.f};
      accg[a][b] = (f32x4){0.f, 0.f, 0.f, 0.f};
    }

  for (int kt = 0; kt < 8; ++kt) {
    __syncthreads();
#pragma unroll
    for (int p = 0; p < 2; ++p) {
      const int c = tid + p * 256, row = c >> 3, k8 = (c & 7) * 8;
      const size_t go = (size_t)(r0 + row) * 512 + kt * 64 + k8;
      const int si = row * 64 + (k8 ^ ((row & 7) << 3));
      *(bf16x8*)&Ash[si] = *(const bf16x8*)(ofhi + go);
      *(bf16x8*)&Asl[si] = *(const bf16x8*)(oflo + go);
    }
#pragma unroll
    for (int p = 0; p < 4; ++p) {
      const int c = tid + p * 256, row = c >> 3, k8 = (c & 7) * 8;
      const int si = row * 64 + (k8 ^ ((row & 7) << 3));
      const size_t go = (size_t)(n0 + row) * 512 + kt * 64 + k8;
      *(bf16x8*)&Bfh[si] = *(const bf16x8*)(Wfh + go);
      *(bf16x8*)&Bfl[si] = *(const bf16x8*)(Wfl + go);
      *(bf16x8*)&Bgh[si] = *(const bf16x8*)(Wgh + go);
      *(bf16x8*)&Bgl[si] = *(const bf16x8*)(Wgl + go);
    }
    __syncthreads();
#pragma unroll
    for (int kf = 0; kf < 2; ++kf) {
      const int kb = kf * 32 + l4 * 8;
      bf16x8 ah[2], al2[2];
#pragma unroll
      for (int rb = 0; rb < 2; ++rb) {
        const int ar = wr * 32 + rb * 16 + l15;
        const int si = ar * 64 + (kb ^ ((ar & 7) << 3));
        ah[rb] = *(bf16x8*)&Ash[si]; al2[rb] = *(bf16x8*)&Asl[si];
      }
#pragma unroll
      for (int cb = 0; cb < 4; ++cb) {
        const int br = wc * 64 + cb * 16 + l15;
        const int si = br * 64 + (kb ^ ((br & 7) << 3));
        const bf16x8 fh = *(bf16x8*)&Bfh[si];
        const bf16x8 fl = *(bf16x8*)&Bfl[si];
        const bf16x8 gh = *(bf16x8*)&Bgh[si];
        const bf16x8 gl = *(bf16x8*)&Bgl[si];
#pragma unroll
        for (int rb = 0; rb < 2; ++rb) {
          accf[rb][cb] = __builtin_amdgcn_mfma_f32_16x16x32_bf16(al2[rb], fh, accf[rb][cb], 0, 0, 0);
          accf[rb][cb] = __builtin_amdgcn_mfma_f32_16x16x32_bf16(ah[rb], fl, accf[rb][cb], 0, 0, 0);
          accf[rb][cb] = __builtin_amdgcn_mfma_f32_16x16x32_bf16(ah[rb], fh, accf[rb][cb], 0, 0, 0);
          accg[rb][cb] = __builtin_amdgcn_mfma_f32_16x16x32_bf16(al2[rb], gh, accg[rb][cb], 0, 0, 0);
          accg[rb][cb] = __builtin_amdgcn_mfma_f32_16x16x32_bf16(ah[rb], gl, accg[rb][cb], 0, 0, 0);
          accg[rb][cb] = __builtin_amdgcn_mfma_f32_16x16x32_bf16(ah[rb], gh, accg[rb][cb], 0, 0, 0);
        }
      }
    }
  }
#pragma unroll
  for (int cb = 0; cb < 4; ++cb) {
    const int col = n0 + wc * 64 + cb * 16 + l15;
    const float bf4 = bfc[col];
    const float bg4 = bg[col];
#pragma unroll
    for (int rb = 0; rb < 2; ++rb)
#pragma unroll
      for (int ri = 0; ri < 4; ++ri) {
        const int row = r0 + wr * 32 + rb * 16 + l4 * 4 + ri;
        const float f = accf[rb][cb][ri] + bf4;
        const float g = accg[rb][cb][ri] + bg4;
        out[(size_t)row * 512 + col] = tanhf(f) / (1.f + __expf(-g));
      }
  }
}

extern "C" void kernel_launch(void* const* d_in, const int* in_sizes, int n_in,
                              void* d_out, int out_size, void* d_ws, size_t ws_size,
                              hipStream_t stream) {
  const float* q   = (const float*)d_in[0];
  const float* k   = (const float*)d_in[1];
  const float* v   = (const float*)d_in[2];
  const float* Wq  = (const float*)d_in[3];
  const float* bq  = (const float*)d_in[4];
  const float* Wk  = (const float*)d_in[5];
  const float* bk  = (const float*)d_in[6];
  const float* Wv  = (const float*)d_in[7];
  const float* bv  = (const float*)d_in[8];
  const float* Wfc = (const float*)d_in[9];
  const float* bfc = (const float*)d_in[10];
  const float* Wg  = (const float*)d_in[11];
  const float* bg  = (const float*)d_in[12];

  float* out  = (float*)d_out;
  float* attn = out + OUT0;                 // (32,1024,1024) score scratch then final

  // qh splits live in the out0 region (8MB, overwritten by out_proj at the end)
  unsigned short* qhh = (unsigned short*)d_out;
  unsigned short* qhl = qhh + (1u << 21);

  // ws (24MB): [0,8M) khh/khl -> later FG; [8,16M) vh; [16M..) Wqkv -> ofhi/oflo
  char* wsb = (char*)d_ws;
  unsigned short* khh  = (unsigned short*)wsb;
  unsigned short* khl  = (unsigned short*)(wsb + (4u << 20));
  float*          vh   = (float*)(wsb + (8u << 20));
  unsigned short* Wqkv = (unsigned short*)(wsb + (16u << 20));
  unsigned short* ofhi = (unsigned short*)(wsb + (16u << 20));
  unsigned short* oflo = (unsigned short*)(wsb + (20u << 20));
  unsigned short* FG   = (unsigned short*)wsb;

  convW_kernel<<<dim3(256, 1, 3), 256, 0, stream>>>(Wq, Wk, Wv, Wqkv);
  qkv_mfma_kernel<<<dim3(64, 4, 3), 256, 0, stream>>>(q, k, v, Wqkv, bq, bk, bv,
                                                      qhh, qhl, khh, khl, vh);
  scores_mfma_kernel<<<dim3(16, 16, 32), 256, 0, stream>>>(qhh, qhl, khh, khl, attn);
  convW_kernel<<<dim3(256, 1, 2), 256, 0, stream>>>(Wfc, Wg, Wg, FG);
  sparse_row_kernel<<<dim3(8192), 256, 0, stream>>>(attn, vh, ofhi, oflo);
  out_proj_mfma_kernel<<<dim3(64, 4), 256, 0, stream>>>(ofhi, oflo, FG, bfc, bg, out);
}